// Round 1
// baseline (1044.910 us; speedup 1.0000x reference)
//
#include <hip/hip_runtime.h>
#include <math.h>

#define EMB 1024
#define NHEADS 16
#define HDIM 64
#define BATCH 2
#define SEQ 2048
#define MROWS (BATCH*SEQ)   /* 4096 */
#define LN_EPS 1e-5f

// ---------------------------------------------------------------------------
// GEMM (NT): C[M,N] = A[M,K] @ B[N,K]^T (+ bias). Both A and B row-major with
// contiguous K — ideal coalesced float4 loads on both operands.
// BM=128, BN=64, BK=16, 256 threads, 8x4 microtile per thread.
// ---------------------------------------------------------------------------
template<bool BIAS>
__global__ __launch_bounds__(256)
void gemm_nt(const float* __restrict__ A, const float* __restrict__ Bm,
             const float* __restrict__ bias, float* __restrict__ C,
             int M, int N, int K)
{
    __shared__ float As[16][132];   // [k][m], pad 132 (528B rows: 16B aligned)
    __shared__ float Bs[16][68];    // [k][n], pad 68  (272B rows: 16B aligned)

    const int t  = threadIdx.x;
    const int tx = t & 15;          // n-block  (4 cols)
    const int ty = t >> 4;          // m-block  (8 rows)
    const int m0 = blockIdx.y * 128;
    const int n0 = blockIdx.x * 64;

    const int lrow = t >> 2;        // 0..63
    const int lk4  = t & 3;         // 0..3 -> float4 within 16-wide K slab

    float acc[8][4];
    #pragma unroll
    for (int i = 0; i < 8; ++i)
        #pragma unroll
        for (int j = 0; j < 4; ++j) acc[i][j] = 0.f;

    for (int k0 = 0; k0 < K; k0 += 16) {
        // stage A tile (128x16) transposed -> As[k][m]
        #pragma unroll
        for (int it = 0; it < 2; ++it) {
            const int r = lrow + it * 64;
            const float4 v = *(const float4*)&A[(size_t)(m0 + r) * K + k0 + lk4 * 4];
            As[lk4*4+0][r] = v.x; As[lk4*4+1][r] = v.y;
            As[lk4*4+2][r] = v.z; As[lk4*4+3][r] = v.w;
        }
        // stage B tile (64x16) transposed -> Bs[k][n]
        {
            const float4 v = *(const float4*)&Bm[(size_t)(n0 + lrow) * K + k0 + lk4 * 4];
            Bs[lk4*4+0][lrow] = v.x; Bs[lk4*4+1][lrow] = v.y;
            Bs[lk4*4+2][lrow] = v.z; Bs[lk4*4+3][lrow] = v.w;
        }
        __syncthreads();

        #pragma unroll
        for (int k = 0; k < 16; ++k) {
            const float4 a0 = *(const float4*)&As[k][ty*8];
            const float4 a1 = *(const float4*)&As[k][ty*8+4];
            const float4 b0 = *(const float4*)&Bs[k][tx*4];
            const float am[8] = {a0.x,a0.y,a0.z,a0.w,a1.x,a1.y,a1.z,a1.w};
            const float bn[4] = {b0.x,b0.y,b0.z,b0.w};
            #pragma unroll
            for (int i = 0; i < 8; ++i)
                #pragma unroll
                for (int j = 0; j < 4; ++j)
                    acc[i][j] = fmaf(am[i], bn[j], acc[i][j]);
        }
        __syncthreads();
    }

    float4 bb = make_float4(0.f, 0.f, 0.f, 0.f);
    if (BIAS) bb = *(const float4*)&bias[n0 + tx*4];
    #pragma unroll
    for (int i = 0; i < 8; ++i) {
        float4 o;
        o.x = acc[i][0] + bb.x; o.y = acc[i][1] + bb.y;
        o.z = acc[i][2] + bb.z; o.w = acc[i][3] + bb.w;
        *(float4*)&C[(size_t)(m0 + ty*8 + i) * N + n0 + tx*4] = o;
    }
}

// ---------------------------------------------------------------------------
// Per-head LayerNorm over 64-wide contiguous rows, fused with emb^(-1/4).
// One wave per row; 4 rows per 256-thread block.
// ---------------------------------------------------------------------------
__global__ __launch_bounds__(256)
void ln_head(float* __restrict__ X, const float* __restrict__ g,
             const float* __restrict__ b, float scale, int nrows)
{
    const int w    = blockIdx.x * 4 + (threadIdx.x >> 6);
    const int lane = threadIdx.x & 63;
    if (w >= nrows) return;
    const size_t idx = (size_t)w * 64 + lane;
    const float v = X[idx];

    float s = v;
    #pragma unroll
    for (int m = 32; m >= 1; m >>= 1) s += __shfl_xor(s, m);
    const float mu = s * (1.f / 64.f);

    const float d  = v - mu;
    float s2 = d * d;
    #pragma unroll
    for (int m = 32; m >= 1; m >>= 1) s2 += __shfl_xor(s2, m);
    const float var = s2 * (1.f / 64.f);

    const float xhat = d * rsqrtf(var + LN_EPS);
    X[idx] = (xhat * g[lane] + b[lane]) * scale;
}

// ---------------------------------------------------------------------------
// Causal flash attention, fp32 vector. One block per (b, h, 64-row q tile).
// Q staged transposed in LDS for the whole block; K/V tiles per iteration.
// Online softmax: 4 lanes per row (shfl_xor reductions). Causal tiles skipped.
// ---------------------------------------------------------------------------
__global__ __launch_bounds__(256)
void attn_fwd(const float* __restrict__ Q, const float* __restrict__ K,
              const float* __restrict__ V, float* __restrict__ O)
{
    __shared__ float Qt[64][68];   // [d][q]
    __shared__ float Kt[64][68];   // [d][k]
    __shared__ float Vs[64][68];   // [k][d]
    __shared__ float Sb[64][68];   // scores -> probabilities, [q][k]
    __shared__ float rowm[64], rowl[64], rowsc[64];

    const int t  = threadIdx.x;
    const int qt = blockIdx.x;               // q tile index (0..31)
    const int bh = blockIdx.y;               // b*NHEADS + h
    const int bb = bh >> 4, hh = bh & 15;
    const size_t base = (size_t)bb * SEQ * EMB + (size_t)hh * HDIM;
    const int q0 = qt * 64;

    const int tx = t & 15;                   // k cols (4)
    const int ty = t >> 4;                   // q rows (4)

    // stage Q tile transposed (persists for whole block)
    {
        const int d4 = t & 15, r0 = t >> 4;
        #pragma unroll
        for (int it = 0; it < 4; ++it) {
            const int r = r0 + it * 16;
            const float4 v = *(const float4*)&Q[base + (size_t)(q0 + r) * EMB + d4 * 4];
            Qt[d4*4+0][r] = v.x; Qt[d4*4+1][r] = v.y;
            Qt[d4*4+2][r] = v.z; Qt[d4*4+3][r] = v.w;
        }
    }
    if (t < 64) { rowm[t] = -1e30f; rowl[t] = 0.f; }

    float oacc[4][4];
    #pragma unroll
    for (int i = 0; i < 4; ++i)
        #pragma unroll
        for (int j = 0; j < 4; ++j) oacc[i][j] = 0.f;

    for (int kt = 0; kt <= qt; ++kt) {
        const int k0 = kt * 64;
        // stage K (transposed) + V tiles
        {
            const int d4 = t & 15, r0 = t >> 4;
            #pragma unroll
            for (int it = 0; it < 4; ++it) {
                const int r = r0 + it * 16;
                const float4 kv = *(const float4*)&K[base + (size_t)(k0 + r) * EMB + d4 * 4];
                Kt[d4*4+0][r] = kv.x; Kt[d4*4+1][r] = kv.y;
                Kt[d4*4+2][r] = kv.z; Kt[d4*4+3][r] = kv.w;
                const float4 vv = *(const float4*)&V[base + (size_t)(k0 + r) * EMB + d4 * 4];
                *(float4*)&Vs[r][d4*4] = vv;
            }
        }
        __syncthreads();

        // phase A: S = Q @ K^T (both already emb^-0.25 scaled)
        float s[4][4];
        #pragma unroll
        for (int i = 0; i < 4; ++i)
            #pragma unroll
            for (int j = 0; j < 4; ++j) s[i][j] = 0.f;

        #pragma unroll 4
        for (int d = 0; d < 64; ++d) {
            const float4 a = *(const float4*)&Qt[d][ty*4];
            const float4 b = *(const float4*)&Kt[d][tx*4];
            const float av[4] = {a.x, a.y, a.z, a.w};
            const float bv[4] = {b.x, b.y, b.z, b.w};
            #pragma unroll
            for (int i = 0; i < 4; ++i)
                #pragma unroll
                for (int j = 0; j < 4; ++j)
                    s[i][j] = fmaf(av[i], bv[j], s[i][j]);
        }
        if (kt == qt) {   // causal mask inside diagonal tile (diag kept)
            #pragma unroll
            for (int i = 0; i < 4; ++i)
                #pragma unroll
                for (int j = 0; j < 4; ++j)
                    if (tx*4 + j > ty*4 + i) s[i][j] = -1e30f;
        }
        #pragma unroll
        for (int i = 0; i < 4; ++i) {
            float4 o; o.x = s[i][0]; o.y = s[i][1]; o.z = s[i][2]; o.w = s[i][3];
            *(float4*)&Sb[ty*4 + i][tx*4] = o;
        }
        __syncthreads();

        // phase B: online softmax update, 4 lanes per row
        {
            const int r = t >> 2, qq = t & 3;
            float mloc = -1e30f;
            #pragma unroll
            for (int u = 0; u < 16; ++u) mloc = fmaxf(mloc, Sb[r][qq*16 + u]);
            mloc = fmaxf(mloc, __shfl_xor(mloc, 1));
            mloc = fmaxf(mloc, __shfl_xor(mloc, 2));
            const float mold = rowm[r];
            const float mnew = fmaxf(mold, mloc);
            float ssum = 0.f;
            #pragma unroll
            for (int u = 0; u < 16; ++u) {
                const float p = __expf(Sb[r][qq*16 + u] - mnew);
                Sb[r][qq*16 + u] = p;
                ssum += p;
            }
            ssum += __shfl_xor(ssum, 1);
            ssum += __shfl_xor(ssum, 2);
            if (qq == 0) {
                const float sc = __expf(mold - mnew);
                rowm[r]  = mnew;
                rowl[r]  = rowl[r] * sc + ssum;
                rowsc[r] = sc;
            }
        }
        __syncthreads();

        // phase C: rescale old accumulator, add P @ V
        #pragma unroll
        for (int i = 0; i < 4; ++i) {
            const float sc = rowsc[ty*4 + i];
            #pragma unroll
            for (int j = 0; j < 4; ++j) oacc[i][j] *= sc;
        }
        #pragma unroll 4
        for (int k4 = 0; k4 < 16; ++k4) {
            float4 p[4], v[4];
            #pragma unroll
            for (int i = 0; i < 4; ++i) p[i] = *(const float4*)&Sb[ty*4 + i][k4*4];
            #pragma unroll
            for (int kk = 0; kk < 4; ++kk) v[kk] = *(const float4*)&Vs[k4*4 + kk][tx*4];
            #pragma unroll
            for (int i = 0; i < 4; ++i) {
                const float pv[4] = {p[i].x, p[i].y, p[i].z, p[i].w};
                const float vv0[4] = {v[0].x, v[0].y, v[0].z, v[0].w};
                const float vv1[4] = {v[1].x, v[1].y, v[1].z, v[1].w};
                const float vv2[4] = {v[2].x, v[2].y, v[2].z, v[2].w};
                oacc[i][0] = fmaf(pv[0], vv0[0], oacc[i][0]);
                oacc[i][1] = fmaf(pv[0], vv0[1], oacc[i][1]);
                oacc[i][2] = fmaf(pv[0], vv0[2], oacc[i][2]);
                oacc[i][3] = fmaf(pv[0], vv0[3], oacc[i][3]);
                oacc[i][0] = fmaf(pv[1], vv1[0], oacc[i][0]);
                oacc[i][1] = fmaf(pv[1], vv1[1], oacc[i][1]);
                oacc[i][2] = fmaf(pv[1], vv1[2], oacc[i][2]);
                oacc[i][3] = fmaf(pv[1], vv1[3], oacc[i][3]);
                oacc[i][0] = fmaf(pv[2], vv2[0], oacc[i][0]);
                oacc[i][1] = fmaf(pv[2], vv2[1], oacc[i][1]);
                oacc[i][2] = fmaf(pv[2], vv2[2], oacc[i][2]);
                oacc[i][3] = fmaf(pv[2], vv2[3], oacc[i][3]);
                const float vv3[4] = {v[3].x, v[3].y, v[3].z, v[3].w};
                oacc[i][0] = fmaf(pv[3], vv3[0], oacc[i][0]);
                oacc[i][1] = fmaf(pv[3], vv3[1], oacc[i][1]);
                oacc[i][2] = fmaf(pv[3], vv3[2], oacc[i][2]);
                oacc[i][3] = fmaf(pv[3], vv3[3], oacc[i][3]);
            }
        }
        __syncthreads();
    }

    // epilogue: normalize by row sum, write O in [b, t, h, d] layout
    #pragma unroll
    for (int i = 0; i < 4; ++i) {
        const float inv = 1.f / rowl[ty*4 + i];
        float4 o;
        o.x = oacc[i][0] * inv; o.y = oacc[i][1] * inv;
        o.z = oacc[i][2] * inv; o.w = oacc[i][3] * inv;
        *(float4*)&O[base + (size_t)(q0 + ty*4 + i) * EMB + tx*4] = o;
    }
}

// ---------------------------------------------------------------------------
extern "C" void kernel_launch(void* const* d_in, const int* in_sizes, int n_in,
                              void* d_out, int out_size, void* d_ws, size_t ws_size,
                              hipStream_t stream)
{
    const float* x  = (const float*)d_in[0];
    const float* Wk = (const float*)d_in[1];
    const float* Wq = (const float*)d_in[2];
    const float* Wv = (const float*)d_in[3];
    const float* Wu = (const float*)d_in[4];
    const float* bu = (const float*)d_in[5];
    const float* kg = (const float*)d_in[6];
    const float* kb = (const float*)d_in[7];
    const float* qg = (const float*)d_in[8];
    const float* qb = (const float*)d_in[9];
    float* out = (float*)d_out;

    const size_t NELEM = (size_t)MROWS * EMB;       // 4,194,304 floats = 16 MB
    float* Kb = (float*)d_ws;                        // needs 64 MB of ws total
    float* Qb = Kb + NELEM;
    float* Vb = Qb + NELEM;
    float* Ob = Vb + NELEM;

    const dim3 gg(EMB / 64, MROWS / 128);            // (16, 32)

    gemm_nt<false><<<gg, 256, 0, stream>>>(x, Wk, nullptr, Kb, MROWS, EMB, EMB);
    gemm_nt<false><<<gg, 256, 0, stream>>>(x, Wq, nullptr, Qb, MROWS, EMB, EMB);
    gemm_nt<false><<<gg, 256, 0, stream>>>(x, Wv, nullptr, Vb, MROWS, EMB, EMB);

    const float inv4 = 0.17677669529663687f;         // 1024^(-1/4) = 2^(-2.5)
    const int head_rows = MROWS * NHEADS;            // 65536 per tensor
    ln_head<<<head_rows / 4, 256, 0, stream>>>(Kb, kg, kb, inv4, head_rows);
    ln_head<<<head_rows / 4, 256, 0, stream>>>(Qb, qg, qb, inv4, head_rows);

    attn_fwd<<<dim3(SEQ / 64, BATCH * NHEADS), 256, 0, stream>>>(Qb, Kb, Vb, Ob);

    gemm_nt<true><<<gg, 256, 0, stream>>>(Ob, Wu, bu, out, MROWS, EMB, EMB);
}